// Round 2
// baseline (914.865 us; speedup 1.0000x reference)
//
#include <hip/hip_runtime.h>
#include <stdint.h>
#include <stddef.h>

#define NROWS 65536
#define EDIM  256
#define NE    1024

// d_out element offsets (f32): [loss][z_q_st 16777216][perp][enc 67108864][idx 65536]
static const long long OFF_ZQ   = 1LL;
static const long long OFF_PERP = 16777217LL;
static const long long OFF_ENC  = 16777218LL;
static const long long OFF_IDX  = 83886082LL;

// ---------------------------------------------------------------------------
// Kernel 0: row norms of z (65536) and emb (1024); zero histogram.
// Accumulation order of the norms is free (per-row constant offsets shift all
// d_j by an exact multiple of the result ulp grid -> argmin pattern preserved).
// ---------------------------------------------------------------------------
__global__ __launch_bounds__(256) void k_norms(const float* __restrict__ z,
                                               const float* __restrict__ emb,
                                               float* __restrict__ znorm,
                                               float* __restrict__ enorm,
                                               unsigned int* __restrict__ hist) {
  if (blockIdx.x == 0) {
    for (int i = threadIdx.x; i < NE; i += 256) hist[i] = 0u;
  }
  int gw   = (int)(((size_t)blockIdx.x * 256 + threadIdx.x) >> 6);  // global wave
  int lane = threadIdx.x & 63;
  if (gw < NROWS) {
    float4 v = ((const float4*)(z + (size_t)gw * EDIM))[lane];  // 64 lanes * 16B = row
    float s = v.x * v.x + v.y * v.y + v.z * v.z + v.w * v.w;
#pragma unroll
    for (int m = 1; m < 64; m <<= 1) s += __shfl_xor(s, m);
    if (lane == 0) znorm[gw] = s;
  } else if (gw < NROWS + NE) {
    int er = gw - NROWS;
    float4 v = ((const float4*)(emb + (size_t)er * EDIM))[lane];
    float s = v.x * v.x + v.y * v.y + v.z * v.z + v.w * v.w;
#pragma unroll
    for (int m = 1; m < 64; m <<= 1) s += __shfl_xor(s, m);
    if (lane == 0) enorm[er] = s;
  }
}

// ---------------------------------------------------------------------------
// Kernel 1: fused fp32 GEMM + argmin. 512 blocks, each owns 128 rows and all
// 1024 codes (8 col-iters of 128) so the argmin is block-local.
// BK=32 K-panels staged in LDS (transposed), 8x8 micro-tile per thread.
// b-panel uses a staggered layout: column-group g (8 floats) lives at float
// offset g*8 + (g>>2)*4, row stride 144. Read offsets tx*8+(tx>>2)*4 then hit
// all 8 bank-quads with exactly 2 addresses each (2-way = free) instead of
// 4 addresses on 4 quads (4-way conflict) with the naive layout.
// Also writes the 268 MB of one-hot zeros, interleaved so stores overlap the
// VALU-bound compute. d replicates the reference rounding exactly:
//   p   = chained fmaf, ascending k            (matches library GEMM accum)
//   t   = znorm[r] + enorm[c]                  (one fp32 rounding)
//   d   = fmaf(-2, p, t)                       (== round(t - 2p))
// Tie-break: smallest index (== jnp.argmin first-occurrence).
// ---------------------------------------------------------------------------
#define BSTRIDE 144

__global__ __launch_bounds__(256, 2) void k_gemm(const float* __restrict__ z,
                                                 const float* __restrict__ emb,
                                                 const float* __restrict__ znorm,
                                                 const float* __restrict__ enorm,
                                                 float* __restrict__ out) {
  __shared__ float aT[32][128];          // 16 KB  zT[k][row]
  __shared__ float bTf[32 * BSTRIDE];    // 18 KB  eT[k][swizzled col]
  __shared__ float zn_s[128];
  __shared__ float en_s[NE];             // 4 KB

  const int tid   = threadIdx.x;
  const int tx    = tid & 15;     // 16 col-groups of 8
  const int ty    = tid >> 4;     // 16 row-groups of 8
  const int rbase = blockIdx.x * 128;
  const int sr    = tid >> 1;     // staging row/col 0..127
  const int sh    = tid & 1;      // staging half (16 floats each)
  const int pc    = sr + ((sr >> 5) << 2);          // swizzled b column slot
  const int rb    = tx * 8 + ((tx >> 2) << 2);      // swizzled b read base

  if (tid < 128) zn_s[tid] = znorm[rbase + tid];
  for (int i = tid; i < NE; i += 256) en_s[i] = enorm[i];

  float dmin[8];
  int   imin[8];
#pragma unroll
  for (int i = 0; i < 8; ++i) { dmin[i] = 3.402823466e+38f; imin[i] = 0; }

  // this block's slice of the one-hot zero fill: 128 rows * 1024 = 131072 f32
  float2* encz = (float2*)(out + OFF_ENC) + (size_t)blockIdx.x * 65536;

#pragma unroll 1
  for (int ci = 0; ci < 8; ++ci) {
    float acc[8][8];
#pragma unroll
    for (int i = 0; i < 8; ++i)
#pragma unroll
      for (int j = 0; j < 8; ++j) acc[i][j] = 0.f;

#pragma unroll 1
    for (int kp = 0; kp < 8; ++kp) {
      const int kbase = kp * 32;
      // issue global loads before the barrier (overlap with prev compute tail)
      const float* zsrc = z + (size_t)(rbase + sr) * EDIM + kbase + sh * 16;
      float4 av0 = ((const float4*)zsrc)[0];
      float4 av1 = ((const float4*)zsrc)[1];
      float4 av2 = ((const float4*)zsrc)[2];
      float4 av3 = ((const float4*)zsrc)[3];
      const float* esrc = emb + (size_t)(ci * 128 + sr) * EDIM + kbase + sh * 16;
      float4 bv0 = ((const float4*)esrc)[0];
      float4 bv1 = ((const float4*)esrc)[1];
      float4 bv2 = ((const float4*)esrc)[2];
      float4 bv3 = ((const float4*)esrc)[3];

      __syncthreads();  // previous compute phase done; LDS free to overwrite

      const int kb = sh * 16;
      float avf[16] = {av0.x, av0.y, av0.z, av0.w, av1.x, av1.y, av1.z, av1.w,
                       av2.x, av2.y, av2.z, av2.w, av3.x, av3.y, av3.z, av3.w};
      float bvf[16] = {bv0.x, bv0.y, bv0.z, bv0.w, bv1.x, bv1.y, bv1.z, bv1.w,
                       bv2.x, bv2.y, bv2.z, bv2.w, bv3.x, bv3.y, bv3.z, bv3.w};
#pragma unroll
      for (int w = 0; w < 16; ++w) aT[kb + w][sr] = avf[w];
#pragma unroll
      for (int w = 0; w < 16; ++w) bTf[(kb + w) * BSTRIDE + pc] = bvf[w];

      __syncthreads();

      // one-hot zero stores: fire-and-forget, retire during this compute phase
      {
        float2 zz = make_float2(0.f, 0.f);
        float2* zs = encz + (size_t)(ci * 8 + kp) * 1024 + (size_t)tid * 4;
        zs[0] = zz; zs[1] = zz; zs[2] = zz; zs[3] = zz;
      }

#pragma unroll
      for (int k = 0; k < 32; ++k) {
        float a[8], b[8];
        *(float4*)&a[0] = *(const float4*)&aT[k][ty * 8];
        *(float4*)&a[4] = *(const float4*)&aT[k][ty * 8 + 4];
        const float* brow = &bTf[k * BSTRIDE + rb];
        *(float4*)&b[0] = *(const float4*)brow;
        *(float4*)&b[4] = *(const float4*)(brow + 4);
#pragma unroll
        for (int i = 0; i < 8; ++i)
#pragma unroll
          for (int j = 0; j < 8; ++j) acc[i][j] = fmaf(a[i], b[j], acc[i][j]);
      }
    }

    // distances + running argmin for this 128-col slab
#pragma unroll
    for (int i = 0; i < 8; ++i) {
      float znr = zn_s[ty * 8 + i];
#pragma unroll
      for (int j = 0; j < 8; ++j) {
        int   c = ci * 128 + tx * 8 + j;
        float t = znr + en_s[c];
        float d = fmaf(-2.f, acc[i][j], t);
        if (d < dmin[i]) { dmin[i] = d; imin[i] = c; }  // strict <: first index wins
      }
    }
  }

  // reduce over the 16 tx lanes (lane bits 0..3), keep smallest-d then smallest-idx
#pragma unroll
  for (int i = 0; i < 8; ++i) {
    float d  = dmin[i];
    int   ix = imin[i];
#pragma unroll
    for (int m = 1; m < 16; m <<= 1) {
      float od = __shfl_xor(d, m);
      int   oi = __shfl_xor(ix, m);
      if (od < d || (od == d && oi < ix)) { d = od; ix = oi; }
    }
    if (tx == 0) out[(size_t)OFF_IDX + rbase + ty * 8 + i] = (float)ix;
  }
}

// ---------------------------------------------------------------------------
// Kernel 2: per-row gather/scatter. z_q_st = z + (z_q - z) with BOTH roundings
// (bitwise-matching the reference STE, which is NOT bitwise z_q).
// ---------------------------------------------------------------------------
__global__ __launch_bounds__(256) void k_scatter(const float* __restrict__ z,
                                                 const float* __restrict__ emb,
                                                 const int* __restrict__ mask,
                                                 float* __restrict__ out,
                                                 unsigned int* __restrict__ hist,
                                                 float* __restrict__ Spart) {
  int row = blockIdx.x;
  int t   = threadIdx.x;
  int idx = (int)out[(size_t)OFF_IDX + row];  // exact: idx < 2^24
  float zq = emb[(size_t)idx * EDIM + t];
  float zv = z[(size_t)row * EDIM + t];
  out[(size_t)OFF_ZQ + (size_t)row * EDIM + t] = zv + (zq - zv);
  float m    = (float)mask[row];
  float diff = (zq - zv) * m;
  float p    = diff * diff;
#pragma unroll
  for (int s = 1; s < 64; s <<= 1) p += __shfl_xor(p, s);
  __shared__ float w4[4];
  if ((t & 63) == 0) w4[t >> 6] = p;
  __syncthreads();
  if (t == 0) {
    Spart[row] = (w4[0] + w4[1]) + (w4[2] + w4[3]);
    atomicAdd(&hist[idx], 1u);
    out[(size_t)OFF_ENC + (size_t)row * NE + idx] = 1.0f;
  }
}

// ---------------------------------------------------------------------------
// Kernel 3: finalize loss + perplexity. e_mean = count/65536 is exact in fp32;
// per-bin fp32 terms match the reference elementwise, summed in double.
// ---------------------------------------------------------------------------
__global__ __launch_bounds__(1024) void k_final(const int* __restrict__ mask,
                                                const unsigned int* __restrict__ hist,
                                                const float* __restrict__ Spart,
                                                float* __restrict__ out) {
  int t = threadIdx.x;  // 1024
  int ms = 0;
  for (int i = t; i < NROWS; i += 1024) ms += mask[i];
  double sp = 0.0;
  for (int i = t; i < NROWS; i += 1024) sp += (double)Spart[i];
  double ent = 0.0;
  {
    int i = t;  // exactly one bin per thread
    float em = (float)hist[i] * (1.0f / 65536.0f);   // exact
    float lg = logf(em + 1e-10f);
    ent = (double)(em * lg);
  }
#pragma unroll
  for (int m = 1; m < 64; m <<= 1) {
    ms  += __shfl_xor(ms, m);
    sp  += __shfl_xor(sp, m);
    ent += __shfl_xor(ent, m);
  }
  __shared__ double redS[16], redE[16];
  __shared__ int    redM[16];
  int w = t >> 6;
  if ((t & 63) == 0) { redS[w] = sp; redE[w] = ent; redM[w] = ms; }
  __syncthreads();
  if (t == 0) {
    double S = 0.0, E = 0.0; int M = 0;
    for (int i = 0; i < 16; ++i) { S += redS[i]; E += redE[i]; M += redM[i]; }
    float denom = (float)M + 1e-6f;              // mask sum is integer-exact in fp32
    float Sf    = (float)S;
    float cl    = Sf / denom;                    // commitment == codebook numerically
    out[0] = cl + 0.25f * cl;                    // loss = cl + BETA*cl
    out[(size_t)OFF_PERP] = expf((float)(-E));
  }
}

// ---------------------------------------------------------------------------
extern "C" void kernel_launch(void* const* d_in, const int* in_sizes, int n_in,
                              void* d_out, int out_size, void* d_ws, size_t ws_size,
                              hipStream_t stream) {
  const float* z    = (const float*)d_in[0];
  const int*   mask = (const int*)d_in[1];
  const float* emb  = (const float*)d_in[2];
  float*       out  = (float*)d_out;

  float*        znorm = (float*)d_ws;            // 65536
  float*        enorm = znorm + NROWS;           // 1024
  unsigned int* hist  = (unsigned int*)(enorm + NE);   // 1024
  float*        Spart = (float*)(hist + NE);     // 65536   (total ws ~ 528 KB)

  k_norms  <<<16640, 256, 0, stream>>>(z, emb, znorm, enorm, hist);
  k_gemm   <<<512,   256, 0, stream>>>(z, emb, znorm, enorm, out);
  k_scatter<<<NROWS, 256, 0, stream>>>(z, emb, mask, out, hist, Spart);
  k_final  <<<1,    1024, 0, stream>>>(mask, hist, Spart, out);
}

// Round 3
// 891.244 us; speedup vs baseline: 1.0265x; 1.0265x over previous
//
#include <hip/hip_runtime.h>
#include <stdint.h>
#include <stddef.h>

#define NROWS 65536
#define EDIM  256
#define NE    1024

// d_out element offsets (f32): [loss][z_q_st 16777216][perp][enc 67108864][idx 65536]
static const long long OFF_ZQ   = 1LL;
static const long long OFF_PERP = 16777217LL;
static const long long OFF_ENC  = 16777218LL;
static const long long OFF_IDX  = 83886082LL;

// ---------------------------------------------------------------------------
// Kernel 0: row norms of z (65536) and emb (1024); zero histogram; init keys.
// znorm/enorm accumulation kept BITWISE identical to the round-2 passing run.
// ---------------------------------------------------------------------------
__global__ __launch_bounds__(256) void k_norms(const float* __restrict__ z,
                                               const float* __restrict__ emb,
                                               float* __restrict__ znorm,
                                               float* __restrict__ enorm,
                                               unsigned int* __restrict__ hist,
                                               unsigned long long* __restrict__ keys) {
  if (blockIdx.x == 0) {
    for (int i = threadIdx.x; i < NE; i += 256) hist[i] = 0u;
  }
  if (blockIdx.x < 256) {  // 256 blocks x 256 threads = 65536 key inits
    keys[blockIdx.x * 256 + threadIdx.x] = 0xFFFFFFFFFFFFFFFFull;
  }
  int gw   = (int)(((size_t)blockIdx.x * 256 + threadIdx.x) >> 6);  // global wave
  int lane = threadIdx.x & 63;
  if (gw < NROWS) {
    float4 v = ((const float4*)(z + (size_t)gw * EDIM))[lane];  // 64 lanes * 16B = row
    float s = v.x * v.x + v.y * v.y + v.z * v.z + v.w * v.w;
#pragma unroll
    for (int m = 1; m < 64; m <<= 1) s += __shfl_xor(s, m);
    if (lane == 0) znorm[gw] = s;
  } else if (gw < NROWS + NE) {
    int er = gw - NROWS;
    float4 v = ((const float4*)(emb + (size_t)er * EDIM))[lane];
    float s = v.x * v.x + v.y * v.y + v.z * v.z + v.w * v.w;
#pragma unroll
    for (int m = 1; m < 64; m <<= 1) s += __shfl_xor(s, m);
    if (lane == 0) enorm[er] = s;
  }
}

// ---------------------------------------------------------------------------
// Kernel 1: fused fp32 GEMM + argmin. 1024 blocks: (row-tile 128) x (col-half
// 512). Col-split doubles blocks/CU (grid was the occupancy binder at R2:
// 512 blocks = 2/CU = 19.9% occupancy, VALUBusy 58%). Partial argmins merge
// via device-scope atomicMin on u64 keys (d_bits<<32|idx): d>0 always here
// (d ~ 256), so the float bit pattern is order-monotone and u64-min
// reproduces exact first-index tie-break. Per-(row,col) d is bitwise
// UNCHANGED (same chained fmaf ascending k; ci slabs just partition cols).
// XCD swizzle: pair blocks {b, b+8} (same row-tile, two col-halves) land on
// the same XCD so the z tile is fetched from HBM once per pair.
// b-panel staggered layout (+4 floats per 4 col-groups): b128 reads hit all
// 8 bank-quads with 2 addrs each (2-way = free).
// Also interleaves the 268 MB one-hot zero-fill into the compute phases.
// ---------------------------------------------------------------------------
#define BSTRIDE 144

__global__ __launch_bounds__(256, 4) void k_gemm(const float* __restrict__ z,
                                                 const float* __restrict__ emb,
                                                 const float* __restrict__ znorm,
                                                 const float* __restrict__ enorm,
                                                 float* __restrict__ out,
                                                 unsigned long long* __restrict__ keys) {
  __shared__ float aT[32][128];          // 16 KB  zT[k][row]
  __shared__ float bTf[32 * BSTRIDE];    // 18 KB  eT[k][swizzled col]
  __shared__ float zn_s[128];
  __shared__ float en_s[512];            // 2 KB (this block's col-half)

  const int tid   = threadIdx.x;
  const int tx    = tid & 15;     // 16 col-groups of 8
  const int ty    = tid >> 4;     // 16 row-groups of 8
  const int b     = blockIdx.x;
  const int ch    = (b >> 3) & 1;                    // col half (pairs share XCD)
  const int rtile = (b & 7) | ((b >> 4) << 3);       // 0..511
  const int rbase = rtile * 128;
  const int cbase = ch * 512;
  const int sr    = tid >> 1;     // staging row/col 0..127
  const int sh    = tid & 1;      // staging half (16 floats each)
  const int pc    = sr + ((sr >> 5) << 2);          // swizzled b column slot
  const int rb    = tx * 8 + ((tx >> 2) << 2);      // swizzled b read base

  if (tid < 128) zn_s[tid] = znorm[rbase + tid];
  for (int i = tid; i < 512; i += 256) en_s[i] = enorm[cbase + i];

  float dmin[8];
  int   imin[8];
#pragma unroll
  for (int i = 0; i < 8; ++i) { dmin[i] = 3.402823466e+38f; imin[i] = 0; }

#pragma unroll 1
  for (int ci = 0; ci < 4; ++ci) {
    float acc[8][8];
#pragma unroll
    for (int i = 0; i < 8; ++i)
#pragma unroll
      for (int j = 0; j < 8; ++j) acc[i][j] = 0.f;

#pragma unroll 1
    for (int kp = 0; kp < 8; ++kp) {
      const int kbase = kp * 32;
      // issue global loads before the barrier (overlap with prev compute tail)
      const float* zsrc = z + (size_t)(rbase + sr) * EDIM + kbase + sh * 16;
      float4 av0 = ((const float4*)zsrc)[0];
      float4 av1 = ((const float4*)zsrc)[1];
      float4 av2 = ((const float4*)zsrc)[2];
      float4 av3 = ((const float4*)zsrc)[3];
      const float* esrc = emb + (size_t)(cbase + ci * 128 + sr) * EDIM + kbase + sh * 16;
      float4 bv0 = ((const float4*)esrc)[0];
      float4 bv1 = ((const float4*)esrc)[1];
      float4 bv2 = ((const float4*)esrc)[2];
      float4 bv3 = ((const float4*)esrc)[3];

      __syncthreads();  // previous compute phase done; LDS free to overwrite

      const int kb = sh * 16;
      float avf[16] = {av0.x, av0.y, av0.z, av0.w, av1.x, av1.y, av1.z, av1.w,
                       av2.x, av2.y, av2.z, av2.w, av3.x, av3.y, av3.z, av3.w};
      float bvf[16] = {bv0.x, bv0.y, bv0.z, bv0.w, bv1.x, bv1.y, bv1.z, bv1.w,
                       bv2.x, bv2.y, bv2.z, bv2.w, bv3.x, bv3.y, bv3.z, bv3.w};
#pragma unroll
      for (int w = 0; w < 16; ++w) aT[kb + w][sr] = avf[w];
#pragma unroll
      for (int w = 0; w < 16; ++w) bTf[(kb + w) * BSTRIDE + pc] = bvf[w];

      __syncthreads();

      // one-hot zero-fill slice: 4 rows x 512 cols per phase, 32 phases
      {
        const int p = ci * 8 + kp;
        float2 zz = make_float2(0.f, 0.f);
        float2* zs = (float2*)(out + OFF_ENC
                               + (size_t)(rbase + p * 4 + (tid >> 6)) * NE
                               + cbase + (tid & 63) * 8);
        zs[0] = zz; zs[1] = zz; zs[2] = zz; zs[3] = zz;
      }

#pragma unroll
      for (int k = 0; k < 32; ++k) {
        float a[8], bfr[8];
        *(float4*)&a[0]   = *(const float4*)&aT[k][ty * 8];
        *(float4*)&a[4]   = *(const float4*)&aT[k][ty * 8 + 4];
        const float* brow = &bTf[k * BSTRIDE + rb];
        *(float4*)&bfr[0] = *(const float4*)brow;
        *(float4*)&bfr[4] = *(const float4*)(brow + 4);
#pragma unroll
        for (int i = 0; i < 8; ++i)
#pragma unroll
          for (int j = 0; j < 8; ++j) acc[i][j] = fmaf(a[i], bfr[j], acc[i][j]);
      }
    }

    // distances + running argmin for this 128-col slab (global col index)
#pragma unroll
    for (int i = 0; i < 8; ++i) {
      float znr = zn_s[ty * 8 + i];
#pragma unroll
      for (int j = 0; j < 8; ++j) {
        int   cl = ci * 128 + tx * 8 + j;
        float t  = znr + en_s[cl];
        float d  = fmaf(-2.f, acc[i][j], t);
        if (d < dmin[i]) { dmin[i] = d; imin[i] = cbase + cl; }  // strict <
      }
    }
  }

  // reduce over the 16 tx lanes, then one atomicMin per row into global keys
#pragma unroll
  for (int i = 0; i < 8; ++i) {
    float d  = dmin[i];
    int   ix = imin[i];
#pragma unroll
    for (int m = 1; m < 16; m <<= 1) {
      float od = __shfl_xor(d, m);
      int   oi = __shfl_xor(ix, m);
      if (od < d || (od == d && oi < ix)) { d = od; ix = oi; }
    }
    if (tx == 0) {
      unsigned long long key =
          ((unsigned long long)__float_as_uint(d) << 32) | (unsigned int)ix;
      atomicMin(&keys[rbase + ty * 8 + i], key);
    }
  }
}

// ---------------------------------------------------------------------------
// Kernel 2: wave-per-row gather/scatter, float4-vectorized, 4 rows per wave.
// z_q_st = z + (z_q - z) with BOTH roundings (bitwise = reference STE).
// Loss partial: same complete balanced binary tree over the 256 elements as
// the round-2 passing run (bits 0-1 in-lane pairwise via __fadd_rn, bits 2-7
// via shfl tree) -> Spart bitwise unchanged. Explicit _rn ops block fma
// contraction that would change rounding.
// ---------------------------------------------------------------------------
__global__ __launch_bounds__(256) void k_scatter(const float* __restrict__ z,
                                                 const float* __restrict__ emb,
                                                 const int* __restrict__ mask,
                                                 float* __restrict__ out,
                                                 unsigned int* __restrict__ hist,
                                                 const unsigned long long* __restrict__ keys,
                                                 float* __restrict__ Spart) {
  int wv   = (int)((blockIdx.x * 256 + threadIdx.x) >> 6);  // 0..16383
  int lane = threadIdx.x & 63;
#pragma unroll 1
  for (int r = 0; r < 4; ++r) {
    int row = wv * 4 + r;
    unsigned long long key = keys[row];
    int idx = (int)(unsigned int)(key & 0xFFFFFFFFull);
    float4 zq = ((const float4*)(emb + (size_t)idx * EDIM))[lane];
    float4 zv = ((const float4*)(z + (size_t)row * EDIM))[lane];
    float4 st;
    st.x = zv.x + (zq.x - zv.x);
    st.y = zv.y + (zq.y - zv.y);
    st.z = zv.z + (zq.z - zv.z);
    st.w = zv.w + (zq.w - zv.w);
    ((float4*)(out + OFF_ZQ + (size_t)row * EDIM))[lane] = st;
    float m  = (float)mask[row];
    float dx = __fmul_rn(__fsub_rn(zq.x, zv.x), m);
    float dy = __fmul_rn(__fsub_rn(zq.y, zv.y), m);
    float dz = __fmul_rn(__fsub_rn(zq.z, zv.z), m);
    float dw = __fmul_rn(__fsub_rn(zq.w, zv.w), m);
    float px = __fmul_rn(dx, dx);
    float py = __fmul_rn(dy, dy);
    float pz = __fmul_rn(dz, dz);
    float pw = __fmul_rn(dw, dw);
    float p  = __fadd_rn(__fadd_rn(px, py), __fadd_rn(pz, pw));
#pragma unroll
    for (int s = 1; s < 64; s <<= 1) p = __fadd_rn(p, __shfl_xor(p, s));
    if (lane == 0) {
      Spart[row] = p;
      atomicAdd(&hist[idx], 1u);
      out[(size_t)OFF_ENC + (size_t)row * NE + idx] = 1.0f;
      out[(size_t)OFF_IDX + row] = (float)idx;
    }
  }
}

// ---------------------------------------------------------------------------
// Kernel 3: finalize loss + perplexity (unchanged from the passing run).
// ---------------------------------------------------------------------------
__global__ __launch_bounds__(1024) void k_final(const int* __restrict__ mask,
                                                const unsigned int* __restrict__ hist,
                                                const float* __restrict__ Spart,
                                                float* __restrict__ out) {
  int t = threadIdx.x;  // 1024
  int ms = 0;
  for (int i = t; i < NROWS; i += 1024) ms += mask[i];
  double sp = 0.0;
  for (int i = t; i < NROWS; i += 1024) sp += (double)Spart[i];
  double ent = 0.0;
  {
    int i = t;  // exactly one bin per thread
    float em = (float)hist[i] * (1.0f / 65536.0f);   // exact
    float lg = logf(em + 1e-10f);
    ent = (double)(em * lg);
  }
#pragma unroll
  for (int m = 1; m < 64; m <<= 1) {
    ms  += __shfl_xor(ms, m);
    sp  += __shfl_xor(sp, m);
    ent += __shfl_xor(ent, m);
  }
  __shared__ double redS[16], redE[16];
  __shared__ int    redM[16];
  int w = t >> 6;
  if ((t & 63) == 0) { redS[w] = sp; redE[w] = ent; redM[w] = ms; }
  __syncthreads();
  if (t == 0) {
    double S = 0.0, E = 0.0; int M = 0;
    for (int i = 0; i < 16; ++i) { S += redS[i]; E += redE[i]; M += redM[i]; }
    float denom = (float)M + 1e-6f;              // mask sum is integer-exact in fp32
    float Sf    = (float)S;
    float cl    = Sf / denom;                    // commitment == codebook numerically
    out[0] = cl + 0.25f * cl;                    // loss = cl + BETA*cl
    out[(size_t)OFF_PERP] = expf((float)(-E));
  }
}

// ---------------------------------------------------------------------------
extern "C" void kernel_launch(void* const* d_in, const int* in_sizes, int n_in,
                              void* d_out, int out_size, void* d_ws, size_t ws_size,
                              hipStream_t stream) {
  const float* z    = (const float*)d_in[0];
  const int*   mask = (const int*)d_in[1];
  const float* emb  = (const float*)d_in[2];
  float*       out  = (float*)d_out;

  // ws layout (Spart aliases znorm, which is dead after k_gemm): ~794 KB
  float*              znorm = (float*)d_ws;                 // 65536 f32
  float*              enorm = znorm + NROWS;                // 1024 f32
  unsigned int*       hist  = (unsigned int*)(enorm + NE);  // 1024 u32
  unsigned long long* keys  = (unsigned long long*)(hist + NE);  // 65536 u64 (8B-aligned)
  float*              Spart = znorm;                        // alias (dead after k_gemm)

  k_norms  <<<16640, 256, 0, stream>>>(z, emb, znorm, enorm, hist, keys);
  k_gemm   <<<1024,  256, 0, stream>>>(z, emb, znorm, enorm, out, keys);
  k_scatter<<<4096,  256, 0, stream>>>(z, emb, mask, out, hist, keys, Spart);
  k_final  <<<1,    1024, 0, stream>>>(mask, hist, Spart, out);
}

// Round 4
// 690.106 us; speedup vs baseline: 1.3257x; 1.2915x over previous
//
#include <hip/hip_runtime.h>
#include <stdint.h>
#include <stddef.h>

#define NROWS 65536
#define EDIM  256
#define NE    1024
#define CAP   24

// d_out element offsets (f32): [loss][z_q_st 16777216][perp][enc 67108864][idx 65536]
static const long long OFF_ZQ   = 1LL;
static const long long OFF_PERP = 16777217LL;
static const long long OFF_ENC  = 16777218LL;
static const long long OFF_IDX  = 83886082LL;

typedef __attribute__((ext_vector_type(8))) short bf16x8;
typedef __attribute__((ext_vector_type(4))) float f32x4;

// RNE float->bf16 (matches hardware cvt semantics for normals; inputs are
// well-scaled normals so NaN/denorm edges don't arise).
__device__ __forceinline__ unsigned short f2bf(float f) {
  unsigned u = __float_as_uint(f);
  return (unsigned short)((u + 0x7FFFu + ((u >> 16) & 1u)) >> 16);
}

// ---------------------------------------------------------------------------
// Kernel 0: row norms of z (65536) and emb (1024) [bitwise = R2/R3 passing
// tree]; zero histogram; emit bf16 codebook copy for the MFMA screen.
// ---------------------------------------------------------------------------
__global__ __launch_bounds__(256) void k_norms(const float* __restrict__ z,
                                               const float* __restrict__ emb,
                                               float* __restrict__ znorm,
                                               float* __restrict__ enorm,
                                               unsigned int* __restrict__ hist,
                                               unsigned short* __restrict__ ebf16) {
  if (blockIdx.x == 0) {
    for (int i = threadIdx.x; i < NE; i += 256) hist[i] = 0u;
  }
  int gw   = (int)(((size_t)blockIdx.x * 256 + threadIdx.x) >> 6);
  int lane = threadIdx.x & 63;
  if (gw < NROWS) {
    float4 v = ((const float4*)(z + (size_t)gw * EDIM))[lane];
    float s = v.x * v.x + v.y * v.y + v.z * v.z + v.w * v.w;
#pragma unroll
    for (int m = 1; m < 64; m <<= 1) s += __shfl_xor(s, m);
    if (lane == 0) znorm[gw] = s;
  } else if (gw < NROWS + NE) {
    int er = gw - NROWS;
    float4 v = ((const float4*)(emb + (size_t)er * EDIM))[lane];
    // bf16 copy of the codebook (RNE) — screen input only, exact path
    // always re-reads the original fp32 emb.
    ushort4 h;
    h.x = f2bf(v.x); h.y = f2bf(v.y); h.z = f2bf(v.z); h.w = f2bf(v.w);
    ((ushort4*)(ebf16 + (size_t)er * EDIM))[lane] = h;
    float s = v.x * v.x + v.y * v.y + v.z * v.z + v.w * v.w;
#pragma unroll
    for (int m = 1; m < 64; m <<= 1) s += __shfl_xor(s, m);
    if (lane == 0) enorm[er] = s;
  }
}

// ---------------------------------------------------------------------------
// Kernel 1: bf16-MFMA screen + exact fp32 refine. Block = 32 rows x all 1024
// codes (argmin block-local). 4 waves; wave w owns cols w*64..w*64+63 over
// both 16-row tiles -> acc[2][4] f32x4 per thread. A (z rows, bf16) staged
// once in LDS (stride 264 shorts -> conflict-free b128 reads); B staged per
// 32-k chunk from the ws bf16 codebook (stride 40 shorts, odd-quad stride).
//
// Screen math: d~ = fmaf(-2, p~, znorm+enorm) where p~ = bf16 MFMA product.
// Rigorous per-row window W = 0.025*sqrt(znorm*enorm_max) + 2e-4 (>=3x the
// analytic |d~ - d| bound: 2*(2^-9+2^-9+2^-18)*sqrt(znorm*enorm) input
// rounding + 2*256*2^-24 accumulation + 2*ulp(256) formation). Every code
// within W of the running row-min is refined with the EXACT R3 chain:
// p = chained fmaf ascending k over original fp32 z,e; d = fmaf(-2,p,t);
// (d, idx) lexicographic min == jnp.argmin first-index semantics. Candidate
// overflow (>CAP, ~never) falls back to exact scan of all 1024 codes.
// ---------------------------------------------------------------------------
__global__ __launch_bounds__(256, 3) void k_screen(
    const float* __restrict__ z, const float* __restrict__ emb,
    const unsigned short* __restrict__ ebf16,
    const float* __restrict__ znorm, const float* __restrict__ enorm,
    float* __restrict__ out, int* __restrict__ idx_ws) {
  __shared__ unsigned short zb[32 * 264];   // 16.9 KB A bf16
  __shared__ unsigned short eb[256 * 40];   // 20.0 KB B chunk bf16
  __shared__ float zn_s[32];
  __shared__ float en_s[NE];                // 4 KB
  __shared__ float wr_s[32];
  __shared__ unsigned int rmin_s[32];       // f32 bits (d~ > 0)
  __shared__ unsigned short cand_s[32][CAP];
  __shared__ int ccnt_s[32];
  __shared__ float bestd_s[32][8];
  __shared__ int   besti_s[32][8];
  __shared__ float emax_s;

  const int tid   = threadIdx.x;
  const int lane  = tid & 63;
  const int wid   = tid >> 6;          // 0..3
  const int l15   = lane & 15;
  const int l4    = lane >> 4;         // 0..3
  const int rbase = blockIdx.x * 32;

  // ---- prologue: stage A as bf16, load norms, init state ----
  {
    int r = tid >> 3, seg = tid & 7;   // 8 threads/row, 32 floats each
    const float* src = z + (size_t)(rbase + r) * EDIM + seg * 32;
    unsigned short* dst = &zb[r * 264 + seg * 32];
#pragma unroll
    for (int q = 0; q < 8; ++q) {
      float4 v = ((const float4*)src)[q];
      ushort4 h;
      h.x = f2bf(v.x); h.y = f2bf(v.y); h.z = f2bf(v.z); h.w = f2bf(v.w);
      ((ushort4*)dst)[q] = h;
    }
  }
  for (int i = tid; i < NE; i += 256) en_s[i] = enorm[i];
  if (tid < 32) {
    zn_s[tid]   = znorm[rbase + tid];
    rmin_s[tid] = 0x7F800000u;  // +inf
    ccnt_s[tid] = 0;
  }
  __syncthreads();
  if (wid == 0) {
    float m = en_s[lane];
    for (int i = lane + 64; i < NE; i += 64) m = fmaxf(m, en_s[i]);
#pragma unroll
    for (int s = 1; s < 64; s <<= 1) m = fmaxf(m, __shfl_xor(m, s));
    if (lane == 0) emax_s = m;
  }
  __syncthreads();
  if (tid < 32) wr_s[tid] = 0.025f * sqrtf(zn_s[tid] * emax_s) + 2.0e-4f;
  // wr_s consumed only after in-loop barriers below.

  // ---- 4 col-slabs of 256 codes ----
  f32x4 acc[2][4];
#pragma unroll 1
  for (int slab = 0; slab < 4; ++slab) {
#pragma unroll
    for (int rt = 0; rt < 2; ++rt)
#pragma unroll
      for (int ct = 0; ct < 4; ++ct) acc[rt][ct] = (f32x4){0.f, 0.f, 0.f, 0.f};

#pragma unroll 1
    for (int ch = 0; ch < 8; ++ch) {
      // issue B-chunk loads (bf16 codebook, L2-resident) before the barrier
      const uint4* bsrc = (const uint4*)(ebf16 + (size_t)(slab * 256 + tid) * EDIM + ch * 32);
      uint4 b0 = bsrc[0], b1 = bsrc[1], b2 = bsrc[2], b3 = bsrc[3];
      __syncthreads();                 // prior chunk's eb reads complete
      uint4* bdst = (uint4*)&eb[tid * 40];
      bdst[0] = b0; ((uint4*)&eb[tid * 40 + 8])[0] = b1;
      ((uint4*)&eb[tid * 40 + 16])[0] = b2; ((uint4*)&eb[tid * 40 + 24])[0] = b3;
      __syncthreads();                 // eb ready

      bf16x8 av0 = *(const bf16x8*)&zb[(0 * 16 + l15) * 264 + ch * 32 + l4 * 8];
      bf16x8 av1 = *(const bf16x8*)&zb[(1 * 16 + l15) * 264 + ch * 32 + l4 * 8];
#pragma unroll
      for (int ct = 0; ct < 4; ++ct) {
        bf16x8 bv = *(const bf16x8*)&eb[(wid * 64 + ct * 16 + l15) * 40 + l4 * 8];
        acc[0][ct] = __builtin_amdgcn_mfma_f32_16x16x32_bf16(av0, bv, acc[0][ct], 0, 0, 0);
        acc[1][ct] = __builtin_amdgcn_mfma_f32_16x16x32_bf16(av1, bv, acc[1][ct], 0, 0, 0);
      }
    }

    // slab row-min: thread min over ct, then shfl over lane bits 0..3
#pragma unroll
    for (int rt = 0; rt < 2; ++rt)
#pragma unroll
      for (int reg = 0; reg < 4; ++reg) {
        int row = rt * 16 + l4 * 4 + reg;
        float znr = zn_s[row];
        float dm = 3.402823466e+38f;
#pragma unroll
        for (int ct = 0; ct < 4; ++ct) {
          int code = slab * 256 + wid * 64 + ct * 16 + l15;
          float t = znr + en_s[code];
          float dt = fmaf(-2.f, acc[rt][ct][reg], t);
          dm = fminf(dm, dt);
        }
#pragma unroll
        for (int m = 1; m < 16; m <<= 1) dm = fminf(dm, __shfl_xor(dm, m));
        if (l15 == 0) atomicMin(&rmin_s[row], __float_as_uint(dm));
      }
    __syncthreads();                   // rmin merged across waves

    // candidate emission vs running min (monotone: false positives only)
#pragma unroll
    for (int rt = 0; rt < 2; ++rt)
#pragma unroll
      for (int reg = 0; reg < 4; ++reg) {
        int row = rt * 16 + l4 * 4 + reg;
        float thr = __uint_as_float(rmin_s[row]) + wr_s[row];
        float znr = zn_s[row];
#pragma unroll
        for (int ct = 0; ct < 4; ++ct) {
          int code = slab * 256 + wid * 64 + ct * 16 + l15;
          float t = znr + en_s[code];
          float dt = fmaf(-2.f, acc[rt][ct][reg], t);
          if (dt <= thr) {
            int p = atomicAdd(&ccnt_s[row], 1);
            if (p < CAP) cand_s[row][p] = (unsigned short)code;
          }
        }
      }
    __syncthreads();                   // lists stable before next slab / refine
  }

  // ---- exact refine: 8 threads per row over its candidate list ----
  {
    const int sub = tid >> 5;          // 0..7
    const int r   = tid & 31;
    const int rowg = rbase + r;
    const float* zp = z + (size_t)rowg * EDIM;
    float bd = 3.402823466e+38f;
    int   bi = 0x7FFFFFFF;
    int cnt = ccnt_s[r];
    if (cnt <= CAP) {
      for (int j = sub; j < cnt; j += 8) {
        int c = cand_s[r][j];
        const float* ep = emb + (size_t)c * EDIM;
        float p = 0.f;
#pragma unroll 8
        for (int k = 0; k < 256; ++k) p = fmaf(zp[k], ep[k], p);  // exact R3 chain
        float t = zn_s[r] + en_s[c];
        float d = fmaf(-2.f, p, t);
        if (d < bd || (d == bd && c < bi)) { bd = d; bi = c; }
      }
    } else {  // overflow fallback: exact scan of all codes (correctness backstop)
      for (int c = sub; c < NE; c += 8) {
        const float* ep = emb + (size_t)c * EDIM;
        float p = 0.f;
#pragma unroll 8
        for (int k = 0; k < 256; ++k) p = fmaf(zp[k], ep[k], p);
        float t = zn_s[r] + en_s[c];
        float d = fmaf(-2.f, p, t);
        if (d < bd || (d == bd && c < bi)) { bd = d; bi = c; }
      }
    }
    bestd_s[r][sub] = bd;
    besti_s[r][sub] = bi;
  }
  __syncthreads();
  if (tid < 32) {
    float bd = bestd_s[tid][0];
    int   bi = besti_s[tid][0];
#pragma unroll
    for (int j = 1; j < 8; ++j) {
      float od = bestd_s[tid][j];
      int   oi = besti_s[tid][j];
      if (od < bd || (od == bd && oi < bi)) { bd = od; bi = oi; }
    }
    idx_ws[rbase + tid] = bi;
    out[(size_t)OFF_IDX + rbase + tid] = (float)bi;
  }
}

// ---------------------------------------------------------------------------
// Kernel 2: per-block one-hot zero-fill (own 16 rows) + barrier, then
// wave-per-row gather/scatter. z_q_st = z + (z_q - z) with BOTH roundings.
// Loss partial: same balanced binary tree as the passing runs (bits 0-1
// in-lane via __fadd_rn pairs, bits 2-7 via shfl) -> Spart bitwise stable.
// ---------------------------------------------------------------------------
__global__ __launch_bounds__(256) void k_scatter(const float* __restrict__ z,
                                                 const float* __restrict__ emb,
                                                 const int* __restrict__ mask,
                                                 float* __restrict__ out,
                                                 unsigned int* __restrict__ hist,
                                                 const int* __restrict__ idx_ws,
                                                 float* __restrict__ Spart) {
  const int tid  = threadIdx.x;
  const int rblk = blockIdx.x * 16;
  // zero this block's 16x1024 one-hot slice (coalesced float4)
  {
    float4 zz = make_float4(0.f, 0.f, 0.f, 0.f);
    float4* encz = (float4*)(out + OFF_ENC + (size_t)rblk * NE);
#pragma unroll
    for (int j = 0; j < 16; ++j) encz[tid + j * 256] = zz;
  }
  __syncthreads();  // zeros retired (vmcnt drain) before 1.0 writes below

  const int wv = tid >> 6, lane = tid & 63;
#pragma unroll
  for (int r = 0; r < 4; ++r) {
    int row = rblk + wv * 4 + r;
    int idx = idx_ws[row];
    float4 zq = ((const float4*)(emb + (size_t)idx * EDIM))[lane];
    float4 zv = ((const float4*)(z + (size_t)row * EDIM))[lane];
    float4 st;
    st.x = zv.x + (zq.x - zv.x);
    st.y = zv.y + (zq.y - zv.y);
    st.z = zv.z + (zq.z - zv.z);
    st.w = zv.w + (zq.w - zv.w);
    ((float4*)(out + OFF_ZQ + (size_t)row * EDIM))[lane] = st;
    float m  = (float)mask[row];
    float dx = __fmul_rn(__fsub_rn(zq.x, zv.x), m);
    float dy = __fmul_rn(__fsub_rn(zq.y, zv.y), m);
    float dz = __fmul_rn(__fsub_rn(zq.z, zv.z), m);
    float dw = __fmul_rn(__fsub_rn(zq.w, zv.w), m);
    float px = __fmul_rn(dx, dx);
    float py = __fmul_rn(dy, dy);
    float pz = __fmul_rn(dz, dz);
    float pw = __fmul_rn(dw, dw);
    float p  = __fadd_rn(__fadd_rn(px, py), __fadd_rn(pz, pw));
#pragma unroll
    for (int s = 1; s < 64; s <<= 1) p = __fadd_rn(p, __shfl_xor(p, s));
    if (lane == 0) {
      Spart[row] = p;
      atomicAdd(&hist[idx], 1u);
      out[(size_t)OFF_ENC + (size_t)row * NE + idx] = 1.0f;
    }
  }
}

// ---------------------------------------------------------------------------
// Kernel 3: finalize loss + perplexity (unchanged from the passing runs).
// ---------------------------------------------------------------------------
__global__ __launch_bounds__(1024) void k_final(const int* __restrict__ mask,
                                                const unsigned int* __restrict__ hist,
                                                const float* __restrict__ Spart,
                                                float* __restrict__ out) {
  int t = threadIdx.x;  // 1024
  int ms = 0;
  for (int i = t; i < NROWS; i += 1024) ms += mask[i];
  double sp = 0.0;
  for (int i = t; i < NROWS; i += 1024) sp += (double)Spart[i];
  double ent = 0.0;
  {
    int i = t;
    float em = (float)hist[i] * (1.0f / 65536.0f);   // exact
    float lg = logf(em + 1e-10f);
    ent = (double)(em * lg);
  }
#pragma unroll
  for (int m = 1; m < 64; m <<= 1) {
    ms  += __shfl_xor(ms, m);
    sp  += __shfl_xor(sp, m);
    ent += __shfl_xor(ent, m);
  }
  __shared__ double redS[16], redE[16];
  __shared__ int    redM[16];
  int w = t >> 6;
  if ((t & 63) == 0) { redS[w] = sp; redE[w] = ent; redM[w] = ms; }
  __syncthreads();
  if (t == 0) {
    double S = 0.0, E = 0.0; int M = 0;
    for (int i = 0; i < 16; ++i) { S += redS[i]; E += redE[i]; M += redM[i]; }
    float denom = (float)M + 1e-6f;
    float Sf    = (float)S;
    float cl    = Sf / denom;
    out[0] = cl + 0.25f * cl;
    out[(size_t)OFF_PERP] = expf((float)(-E));
  }
}

// ---------------------------------------------------------------------------
extern "C" void kernel_launch(void* const* d_in, const int* in_sizes, int n_in,
                              void* d_out, int out_size, void* d_ws, size_t ws_size,
                              hipStream_t stream) {
  const float* z    = (const float*)d_in[0];
  const int*   mask = (const int*)d_in[1];
  const float* emb  = (const float*)d_in[2];
  float*       out  = (float*)d_out;

  // ws layout (~1.01 MB): znorm | enorm | hist | ebf16 | idx_ws ; Spart
  // aliases znorm (dead after k_screen).
  float*          znorm = (float*)d_ws;                        // 65536 f32
  float*          enorm = znorm + NROWS;                       // 1024 f32
  unsigned int*   hist  = (unsigned int*)(enorm + NE);         // 1024 u32
  unsigned short* ebf16 = (unsigned short*)(hist + NE);        // 1024*256 bf16
  int*            idx_ws = (int*)(ebf16 + (size_t)NE * EDIM);  // 65536 i32
  float*          Spart = znorm;                               // alias

  k_norms  <<<16640, 256, 0, stream>>>(z, emb, znorm, enorm, hist, ebf16);
  k_screen <<<2048,  256, 0, stream>>>(z, emb, ebf16, znorm, enorm, out, idx_ws);
  k_scatter<<<4096,  256, 0, stream>>>(z, emb, mask, out, hist, idx_ws, Spart);
  k_final  <<<1,    1024, 0, stream>>>(mask, hist, Spart, out);
}

// Round 5
// 598.598 us; speedup vs baseline: 1.5283x; 1.1529x over previous
//
#include <hip/hip_runtime.h>
#include <stdint.h>
#include <stddef.h>

#define NROWS 65536
#define EDIM  256
#define NE    1024
#define CAP   24

// d_out element offsets (f32): [loss][z_q_st 16777216][perp][enc 67108864][idx 65536]
static const long long OFF_ZQ   = 1LL;
static const long long OFF_PERP = 16777217LL;
static const long long OFF_ENC  = 16777218LL;
static const long long OFF_IDX  = 83886082LL;

typedef __attribute__((ext_vector_type(8))) short bf16x8;
typedef __attribute__((ext_vector_type(4))) float f32x4;

// RNE float->bf16 (same as R4 passing run).
__device__ __forceinline__ unsigned short f2bf(float f) {
  unsigned u = __float_as_uint(f);
  return (unsigned short)((u + 0x7FFFu + ((u >> 16) & 1u)) >> 16);
}

// ---------------------------------------------------------------------------
// Kernel 0 (tiny): emb norms + bf16 codebook + hist zero + global emax.
// enorm tree bitwise = R2/R3/R4 passing runs. emax via SIGNED atomicMax on
// float bits: ws poison 0xAAAAAAAA is negative as int, any positive enorm
// bits wins -> no init pass needed (and identical every launch).
// ---------------------------------------------------------------------------
__global__ __launch_bounds__(256) void k_emb(const float* __restrict__ emb,
                                             float* __restrict__ enorm,
                                             unsigned short* __restrict__ ebf16,
                                             unsigned int* __restrict__ hist,
                                             int* __restrict__ emaxbits) {
  if (blockIdx.x == 0) {
    for (int i = threadIdx.x; i < NE; i += 256) hist[i] = 0u;
  }
  int er   = blockIdx.x * 4 + (threadIdx.x >> 6);  // 256 blocks x 4 waves = 1024 rows
  int lane = threadIdx.x & 63;
  float4 v = ((const float4*)(emb + (size_t)er * EDIM))[lane];
  ushort4 h;
  h.x = f2bf(v.x); h.y = f2bf(v.y); h.z = f2bf(v.z); h.w = f2bf(v.w);
  ((ushort4*)(ebf16 + (size_t)er * EDIM))[lane] = h;
  float s = v.x * v.x + v.y * v.y + v.z * v.z + v.w * v.w;
#pragma unroll
  for (int m = 1; m < 64; m <<= 1) s += __shfl_xor(s, m);
  if (lane == 0) {
    enorm[er] = s;
    atomicMax(emaxbits, (int)__float_as_uint(s));  // s > 0 -> bits order-monotone
  }
}

// ---------------------------------------------------------------------------
// Kernel 1: fully fused per-32-row pipeline. One block owns 32 rows end to
// end: enc zero-fill -> znorm (bitwise R2 tree) + bf16 A staging -> barrier-
// free bf16 MFMA screen (B frags straight from L2, 64 MFMA + 32 loads per
// slab, no syncs inside) -> candidate emission (monotone-safe running min;
// no post-emission barrier) -> exact fp32 refine (R3/R4 bitwise chain,
// (d,idx)-lex min == jnp.argmin first-index) -> gather/STE/Spart/hist/one-hot.
// Window W = 0.025*sqrt(znorm*emax) + 2e-4 >= 3x the analytic |d~-d| bound;
// candidate set is always a superset of codes within W of the screened min,
// so the exact refine winner is invariant to emission races. CAP overflow
// (~never) falls back to an exact 1024-code scan.
// ---------------------------------------------------------------------------
__global__ __launch_bounds__(256, 3) void k_main(
    const float* __restrict__ z, const float* __restrict__ emb,
    const unsigned short* __restrict__ ebf16,
    const float* __restrict__ enorm, const int* __restrict__ mask,
    const int* __restrict__ emaxbits,
    float* __restrict__ out, unsigned int* __restrict__ hist,
    float* __restrict__ Spart) {
  __shared__ unsigned short zb[32 * 264];   // 16.9 KB  A bf16, stride 264
  __shared__ float en_s[NE];                // 4 KB
  __shared__ float zn_s[32];
  __shared__ float wr_s[32];
  __shared__ unsigned int rmin_s[32];
  __shared__ unsigned short cand_s[32][CAP];
  __shared__ int ccnt_s[32];
  __shared__ float bestd_s[32][8];
  __shared__ int   besti_s[32][8];
  __shared__ int   idx_s[32];

  const int tid   = threadIdx.x;
  const int lane  = tid & 63;
  const int wid   = tid >> 6;          // 0..3
  const int l15   = lane & 15;
  const int l4    = lane >> 4;         // 0..3
  const int rbase = blockIdx.x * 32;

  // ---- enc zero-fill for this block's 32x1024 slice (fire-and-forget) ----
  {
    float4 zz = make_float4(0.f, 0.f, 0.f, 0.f);
    float4* encz = (float4*)(out + OFF_ENC + (size_t)rbase * NE);
#pragma unroll
    for (int j = 0; j < 8; ++j) encz[tid + j * 256] = zz;
  }

  if (tid < 32) { rmin_s[tid] = 0x7F800000u; ccnt_s[tid] = 0; }
  for (int i = tid; i < NE; i += 256) en_s[i] = enorm[i];

  // ---- prologue: read z rows (fp32), znorm tree (bitwise R2), stage bf16 A
  {
#pragma unroll 1
    for (int rr = 0; rr < 8; ++rr) {
      int row_l = wid * 8 + rr;
      float4 v = ((const float4*)(z + (size_t)(rbase + row_l) * EDIM))[lane];
      float s = v.x * v.x + v.y * v.y + v.z * v.z + v.w * v.w;
#pragma unroll
      for (int m = 1; m < 64; m <<= 1) s += __shfl_xor(s, m);
      if (lane == 0) zn_s[row_l] = s;
      ushort4 h;
      h.x = f2bf(v.x); h.y = f2bf(v.y); h.z = f2bf(v.z); h.w = f2bf(v.w);
      ((ushort4*)&zb[row_l * 264])[lane] = h;
    }
  }
  __syncthreads();

  const float emaxf = __uint_as_float((unsigned)*emaxbits);
  if (tid < 32) wr_s[tid] = 0.025f * sqrtf(zn_s[tid] * emaxf) + 2.0e-4f;
  // wr_s consumed only after the slab-0 barrier below.

  float znr[2][4];
#pragma unroll
  for (int rt = 0; rt < 2; ++rt)
#pragma unroll
    for (int reg = 0; reg < 4; ++reg) znr[rt][reg] = zn_s[rt * 16 + l4 * 4 + reg];

  // ---- screen: 4 slabs x (8 chunks x 4 ct), barrier-free inner loop ----
#pragma unroll 1
  for (int slab = 0; slab < 4; ++slab) {
    f32x4 acc[2][4];
#pragma unroll
    for (int rt = 0; rt < 2; ++rt)
#pragma unroll
      for (int ct = 0; ct < 4; ++ct) acc[rt][ct] = (f32x4){0.f, 0.f, 0.f, 0.f};

#pragma unroll 4
    for (int ch = 0; ch < 8; ++ch) {
      bf16x8 bv[4];
#pragma unroll
      for (int ct = 0; ct < 4; ++ct)
        bv[ct] = *(const bf16x8*)(ebf16
                    + (size_t)(slab * 256 + wid * 64 + ct * 16 + l15) * EDIM
                    + ch * 32 + l4 * 8);
      bf16x8 av0 = *(const bf16x8*)&zb[(0 * 16 + l15) * 264 + ch * 32 + l4 * 8];
      bf16x8 av1 = *(const bf16x8*)&zb[(1 * 16 + l15) * 264 + ch * 32 + l4 * 8];
#pragma unroll
      for (int ct = 0; ct < 4; ++ct) {
        acc[0][ct] = __builtin_amdgcn_mfma_f32_16x16x32_bf16(av0, bv[ct], acc[0][ct], 0, 0, 0);
        acc[1][ct] = __builtin_amdgcn_mfma_f32_16x16x32_bf16(av1, bv[ct], acc[1][ct], 0, 0, 0);
      }
    }

    // slab row-min (thread over ct, shfl over lane bits 0..3, LDS atomicMin)
#pragma unroll
    for (int rt = 0; rt < 2; ++rt)
#pragma unroll
      for (int reg = 0; reg < 4; ++reg) {
        int row = rt * 16 + l4 * 4 + reg;
        float dm = 3.402823466e+38f;
#pragma unroll
        for (int ct = 0; ct < 4; ++ct) {
          int code = slab * 256 + wid * 64 + ct * 16 + l15;
          float t  = znr[rt][reg] + en_s[code];
          float dt = fmaf(-2.f, acc[rt][ct][reg], t);
          dm = fminf(dm, dt);
        }
#pragma unroll
        for (int m = 1; m < 16; m <<= 1) dm = fminf(dm, __shfl_xor(dm, m));
        if (l15 == 0) atomicMin(&rmin_s[row], __float_as_uint(dm));
      }
    __syncthreads();  // own+prior slab mins merged -> bounded thresholds

    // emission vs running min (monotone: races only ADD false positives)
#pragma unroll
    for (int rt = 0; rt < 2; ++rt)
#pragma unroll
      for (int reg = 0; reg < 4; ++reg) {
        int row = rt * 16 + l4 * 4 + reg;
        float thr = __uint_as_float(rmin_s[row]) + wr_s[row];
#pragma unroll
        for (int ct = 0; ct < 4; ++ct) {
          int code = slab * 256 + wid * 64 + ct * 16 + l15;
          float t  = znr[rt][reg] + en_s[code];
          float dt = fmaf(-2.f, acc[rt][ct][reg], t);
          if (dt <= thr) {
            int p = atomicAdd(&ccnt_s[row], 1);
            if (p < CAP) cand_s[row][p] = (unsigned short)code;
          }
        }
      }
    // no post-emission barrier (monotone-safe)
  }
  __syncthreads();  // all emissions done before refine

  // ---- exact refine: 8 threads per row (bitwise R3/R4 chain) ----
  {
    const int sub  = tid >> 5;         // 0..7
    const int r    = tid & 31;
    const float* zp = z + (size_t)(rbase + r) * EDIM;
    float bd = 3.402823466e+38f;
    int   bi = 0x7FFFFFFF;
    int cnt = ccnt_s[r];
    if (cnt <= CAP) {
      for (int j = sub; j < cnt; j += 8) {
        int c = cand_s[r][j];
        const float* ep = emb + (size_t)c * EDIM;
        float p = 0.f;
#pragma unroll 8
        for (int k = 0; k < 256; ++k) p = fmaf(zp[k], ep[k], p);  // exact chain
        float t = zn_s[r] + en_s[c];
        float d = fmaf(-2.f, p, t);
        if (d < bd || (d == bd && c < bi)) { bd = d; bi = c; }
      }
    } else {  // overflow fallback: exact scan (correctness backstop)
      for (int c = sub; c < NE; c += 8) {
        const float* ep = emb + (size_t)c * EDIM;
        float p = 0.f;
#pragma unroll 8
        for (int k = 0; k < 256; ++k) p = fmaf(zp[k], ep[k], p);
        float t = zn_s[r] + en_s[c];
        float d = fmaf(-2.f, p, t);
        if (d < bd || (d == bd && c < bi)) { bd = d; bi = c; }
      }
    }
    bestd_s[r][sub] = bd;
    besti_s[r][sub] = bi;
  }
  __syncthreads();
  if (tid < 32) {
    float bd = bestd_s[tid][0];
    int   bi = besti_s[tid][0];
#pragma unroll
    for (int j = 1; j < 8; ++j) {
      float od = bestd_s[tid][j];
      int   oi = besti_s[tid][j];
      if (od < bd || (od == bd && oi < bi)) { bd = od; bi = oi; }
    }
    idx_s[tid] = bi;
    out[(size_t)OFF_IDX + rbase + tid] = (float)bi;
  }
  __syncthreads();  // idx_s ready; zero-fill long since drained by barriers

  // ---- fused scatter: STE + Spart (bitwise R4 tree) + hist + one-hot ----
#pragma unroll 1
  for (int rr = 0; rr < 8; ++rr) {
    int row_l = wid * 8 + rr;
    int row   = rbase + row_l;
    int idx   = idx_s[row_l];
    float4 zq = ((const float4*)(emb + (size_t)idx * EDIM))[lane];
    float4 zv = ((const float4*)(z + (size_t)row * EDIM))[lane];
    float4 st;
    st.x = zv.x + (zq.x - zv.x);
    st.y = zv.y + (zq.y - zv.y);
    st.z = zv.z + (zq.z - zv.z);
    st.w = zv.w + (zq.w - zv.w);
    ((float4*)(out + OFF_ZQ + (size_t)row * EDIM))[lane] = st;
    float m  = (float)mask[row];
    float dx = __fmul_rn(__fsub_rn(zq.x, zv.x), m);
    float dy = __fmul_rn(__fsub_rn(zq.y, zv.y), m);
    float dz = __fmul_rn(__fsub_rn(zq.z, zv.z), m);
    float dw = __fmul_rn(__fsub_rn(zq.w, zv.w), m);
    float px = __fmul_rn(dx, dx);
    float py = __fmul_rn(dy, dy);
    float pz = __fmul_rn(dz, dz);
    float pw = __fmul_rn(dw, dw);
    float p  = __fadd_rn(__fadd_rn(px, py), __fadd_rn(pz, pw));
#pragma unroll
    for (int s = 1; s < 64; s <<= 1) p = __fadd_rn(p, __shfl_xor(p, s));
    if (lane == 0) {
      Spart[row] = p;
      atomicAdd(&hist[idx], 1u);
      out[(size_t)OFF_ENC + (size_t)row * NE + idx] = 1.0f;
    }
  }
}

// ---------------------------------------------------------------------------
// Kernel 2: finalize loss + perplexity (bitwise-unchanged from passing runs).
// ---------------------------------------------------------------------------
__global__ __launch_bounds__(1024) void k_final(const int* __restrict__ mask,
                                                const unsigned int* __restrict__ hist,
                                                const float* __restrict__ Spart,
                                                float* __restrict__ out) {
  int t = threadIdx.x;  // 1024
  int ms = 0;
  for (int i = t; i < NROWS; i += 1024) ms += mask[i];
  double sp = 0.0;
  for (int i = t; i < NROWS; i += 1024) sp += (double)Spart[i];
  double ent = 0.0;
  {
    int i = t;
    float em = (float)hist[i] * (1.0f / 65536.0f);   // exact
    float lg = logf(em + 1e-10f);
    ent = (double)(em * lg);
  }
#pragma unroll
  for (int m = 1; m < 64; m <<= 1) {
    ms  += __shfl_xor(ms, m);
    sp  += __shfl_xor(sp, m);
    ent += __shfl_xor(ent, m);
  }
  __shared__ double redS[16], redE[16];
  __shared__ int    redM[16];
  int w = t >> 6;
  if ((t & 63) == 0) { redS[w] = sp; redE[w] = ent; redM[w] = ms; }
  __syncthreads();
  if (t == 0) {
    double S = 0.0, E = 0.0; int M = 0;
    for (int i = 0; i < 16; ++i) { S += redS[i]; E += redE[i]; M += redM[i]; }
    float denom = (float)M + 1e-6f;
    float Sf    = (float)S;
    float cl    = Sf / denom;
    out[0] = cl + 0.25f * cl;
    out[(size_t)OFF_PERP] = expf((float)(-E));
  }
}

// ---------------------------------------------------------------------------
extern "C" void kernel_launch(void* const* d_in, const int* in_sizes, int n_in,
                              void* d_out, int out_size, void* d_ws, size_t ws_size,
                              hipStream_t stream) {
  const float* z    = (const float*)d_in[0];
  const int*   mask = (const int*)d_in[1];
  const float* emb  = (const float*)d_in[2];
  float*       out  = (float*)d_out;

  // ws (~795 KB): Spart | enorm | hist | emaxbits(+pad) | ebf16
  float*          Spart    = (float*)d_ws;                       // 65536 f32
  float*          enorm    = Spart + NROWS;                      // 1024 f32
  unsigned int*   hist     = (unsigned int*)(enorm + NE);        // 1024 u32
  int*            emaxbits = (int*)(hist + NE);                  // 1 i32 (+3 pad)
  unsigned short* ebf16    = (unsigned short*)(emaxbits + 4);    // 1024*256 bf16

  k_emb  <<<256,  256, 0, stream>>>(emb, enorm, ebf16, hist, emaxbits);
  k_main <<<2048, 256, 0, stream>>>(z, emb, ebf16, enorm, mask, emaxbits,
                                    out, hist, Spart);
  k_final<<<1,   1024, 0, stream>>>(mask, hist, Spart, out);
}

// Round 7
// 594.476 us; speedup vs baseline: 1.5389x; 1.0069x over previous
//
#include <hip/hip_runtime.h>
#include <stdint.h>
#include <stddef.h>

#define NROWS 65536
#define EDIM  256
#define NE    1024
#define CAP   24

// d_out element offsets (f32): [loss][z_q_st 16777216][perp][enc 67108864][idx 65536]
static const long long OFF_ZQ   = 1LL;
static const long long OFF_PERP = 16777217LL;
static const long long OFF_ENC  = 16777218LL;
static const long long OFF_IDX  = 83886082LL;

typedef __attribute__((ext_vector_type(8))) short bf16x8;
typedef __attribute__((ext_vector_type(4))) float f32x4;

// RNE float->bf16 (same as R4/R5 passing runs).
__device__ __forceinline__ unsigned short f2bf(float f) {
  unsigned u = __float_as_uint(f);
  return (unsigned short)((u + 0x7FFFu + ((u >> 16) & 1u)) >> 16);
}

// ---------------------------------------------------------------------------
// Kernel 0 (tiny): emb norms + bf16 codebook + hist zero + global emax.
// Bitwise-identical to R5 passing run.
// ---------------------------------------------------------------------------
__global__ __launch_bounds__(256) void k_emb(const float* __restrict__ emb,
                                             float* __restrict__ enorm,
                                             unsigned short* __restrict__ ebf16,
                                             unsigned int* __restrict__ hist,
                                             int* __restrict__ emaxbits) {
  if (blockIdx.x == 0) {
    for (int i = threadIdx.x; i < NE; i += 256) hist[i] = 0u;
  }
  int er   = blockIdx.x * 4 + (threadIdx.x >> 6);
  int lane = threadIdx.x & 63;
  float4 v = ((const float4*)(emb + (size_t)er * EDIM))[lane];
  ushort4 h;
  h.x = f2bf(v.x); h.y = f2bf(v.y); h.z = f2bf(v.z); h.w = f2bf(v.w);
  ((ushort4*)(ebf16 + (size_t)er * EDIM))[lane] = h;
  float s = v.x * v.x + v.y * v.y + v.z * v.z + v.w * v.w;
#pragma unroll
  for (int m = 1; m < 64; m <<= 1) s += __shfl_xor(s, m);
  if (lane == 0) {
    enorm[er] = s;
    atomicMax(emaxbits, (int)__float_as_uint(s));  // s > 0 -> bits order-monotone
  }
}

// ---------------------------------------------------------------------------
// Kernel 1: fused per-32-row pipeline (same algorithm as R5 passing run).
// (a) 2-deep register prefetch of B (global, L2) and A (LDS) across a
// fully-unrolled chunk loop — R5's VGPR=56 showed the compiler serialized
// one 4-load round-trip per 8 MFMAs (~200cy stall / 40cy compute = the
// measured 5% MfmaUtil); (b) nontemporal stores (via native ext-vector f32x4,
// NOT HIP_vector_type — compile fix from R6) for the 268 MB one-hot
// zero-fill and 67 MB z_q_st so the write-once streams stop thrashing
// ebf16/emb out of L2; (c) __launch_bounds__(256,4).
// All arithmetic chains, orders, and tie-breaks bitwise-identical to R5.
// ---------------------------------------------------------------------------
__global__ __launch_bounds__(256, 4) void k_main(
    const float* __restrict__ z, const float* __restrict__ emb,
    const unsigned short* __restrict__ ebf16,
    const float* __restrict__ enorm, const int* __restrict__ mask,
    const int* __restrict__ emaxbits,
    float* __restrict__ out, unsigned int* __restrict__ hist,
    float* __restrict__ Spart) {
  __shared__ unsigned short zb[32 * 264];   // 16.9 KB  A bf16, stride 264
  __shared__ float en_s[NE];                // 4 KB
  __shared__ float zn_s[32];
  __shared__ float wr_s[32];
  __shared__ unsigned int rmin_s[32];
  __shared__ unsigned short cand_s[32][CAP];
  __shared__ int ccnt_s[32];
  __shared__ float bestd_s[32][8];
  __shared__ int   besti_s[32][8];
  __shared__ int   idx_s[32];

  const int tid   = threadIdx.x;
  const int lane  = tid & 63;
  const int wid   = tid >> 6;          // 0..3
  const int l15   = lane & 15;
  const int l4    = lane >> 4;         // 0..3
  const int rbase = blockIdx.x * 32;

  // ---- enc zero-fill for this block's 32x1024 slice (NT, fire-and-forget)
  {
    f32x4 zz = (f32x4){0.f, 0.f, 0.f, 0.f};
    f32x4* encz = (f32x4*)(out + OFF_ENC + (size_t)rbase * NE);
#pragma unroll
    for (int j = 0; j < 8; ++j)
      __builtin_nontemporal_store(zz, encz + tid + j * 256);
  }

  if (tid < 32) { rmin_s[tid] = 0x7F800000u; ccnt_s[tid] = 0; }
  for (int i = tid; i < NE; i += 256) en_s[i] = enorm[i];

  // ---- prologue: read z rows (fp32), znorm tree (bitwise R2), stage bf16 A
  {
#pragma unroll 1
    for (int rr = 0; rr < 8; ++rr) {
      int row_l = wid * 8 + rr;
      float4 v = ((const float4*)(z + (size_t)(rbase + row_l) * EDIM))[lane];
      float s = v.x * v.x + v.y * v.y + v.z * v.z + v.w * v.w;
#pragma unroll
      for (int m = 1; m < 64; m <<= 1) s += __shfl_xor(s, m);
      if (lane == 0) zn_s[row_l] = s;
      ushort4 h;
      h.x = f2bf(v.x); h.y = f2bf(v.y); h.z = f2bf(v.z); h.w = f2bf(v.w);
      ((ushort4*)&zb[row_l * 264])[lane] = h;
    }
  }
  __syncthreads();

  const float emaxf = __uint_as_float((unsigned)*emaxbits);
  if (tid < 32) wr_s[tid] = 0.025f * sqrtf(zn_s[tid] * emaxf) + 2.0e-4f;

  float znr[2][4];
#pragma unroll
  for (int rt = 0; rt < 2; ++rt)
#pragma unroll
    for (int reg = 0; reg < 4; ++reg) znr[rt][reg] = zn_s[rt * 16 + l4 * 4 + reg];

  const unsigned short* pa0 = &zb[l15 * 264 + l4 * 8];
  const unsigned short* pa1 = pa0 + 16 * 264;

  // ---- screen: 4 slabs; inner 8-chunk loop fully unrolled, 2-deep prefetch
#pragma unroll 1
  for (int slab = 0; slab < 4; ++slab) {
    f32x4 acc[2][4];
#pragma unroll
    for (int rt = 0; rt < 2; ++rt)
#pragma unroll
      for (int ct = 0; ct < 4; ++ct) acc[rt][ct] = (f32x4){0.f, 0.f, 0.f, 0.f};

    const unsigned short* eb0 =
        ebf16 + (size_t)(slab * 256 + wid * 64 + l15) * EDIM + l4 * 8;
    const unsigned short* eb1 = eb0 + 16 * EDIM;
    const unsigned short* eb2 = eb0 + 32 * EDIM;
    const unsigned short* eb3 = eb0 + 48 * EDIM;

    bf16x8 cb0 = *(const bf16x8*)(eb0);
    bf16x8 cb1 = *(const bf16x8*)(eb1);
    bf16x8 cb2 = *(const bf16x8*)(eb2);
    bf16x8 cb3 = *(const bf16x8*)(eb3);
    bf16x8 ca0 = *(const bf16x8*)(pa0);
    bf16x8 ca1 = *(const bf16x8*)(pa1);

#define MFMA8()                                                            \
    acc[0][0] = __builtin_amdgcn_mfma_f32_16x16x32_bf16(ca0, cb0, acc[0][0], 0, 0, 0); \
    acc[1][0] = __builtin_amdgcn_mfma_f32_16x16x32_bf16(ca1, cb0, acc[1][0], 0, 0, 0); \
    acc[0][1] = __builtin_amdgcn_mfma_f32_16x16x32_bf16(ca0, cb1, acc[0][1], 0, 0, 0); \
    acc[1][1] = __builtin_amdgcn_mfma_f32_16x16x32_bf16(ca1, cb1, acc[1][1], 0, 0, 0); \
    acc[0][2] = __builtin_amdgcn_mfma_f32_16x16x32_bf16(ca0, cb2, acc[0][2], 0, 0, 0); \
    acc[1][2] = __builtin_amdgcn_mfma_f32_16x16x32_bf16(ca1, cb2, acc[1][2], 0, 0, 0); \
    acc[0][3] = __builtin_amdgcn_mfma_f32_16x16x32_bf16(ca0, cb3, acc[0][3], 0, 0, 0); \
    acc[1][3] = __builtin_amdgcn_mfma_f32_16x16x32_bf16(ca1, cb3, acc[1][3], 0, 0, 0);

#define STEP(ch)                                                           \
    {                                                                      \
      bf16x8 nb0 = *(const bf16x8*)(eb0 + ((ch) + 1) * 32);                \
      bf16x8 nb1 = *(const bf16x8*)(eb1 + ((ch) + 1) * 32);                \
      bf16x8 nb2 = *(const bf16x8*)(eb2 + ((ch) + 1) * 32);                \
      bf16x8 nb3 = *(const bf16x8*)(eb3 + ((ch) + 1) * 32);                \
      bf16x8 na0 = *(const bf16x8*)(pa0 + ((ch) + 1) * 32);                \
      bf16x8 na1 = *(const bf16x8*)(pa1 + ((ch) + 1) * 32);                \
      MFMA8();                                                             \
      cb0 = nb0; cb1 = nb1; cb2 = nb2; cb3 = nb3; ca0 = na0; ca1 = na1;    \
    }

    STEP(0) STEP(1) STEP(2) STEP(3) STEP(4) STEP(5) STEP(6)
    MFMA8();
#undef STEP
#undef MFMA8

    // slab row-min (thread over ct, shfl over lane bits 0..3, LDS atomicMin)
#pragma unroll
    for (int rt = 0; rt < 2; ++rt)
#pragma unroll
      for (int reg = 0; reg < 4; ++reg) {
        int row = rt * 16 + l4 * 4 + reg;
        float dm = 3.402823466e+38f;
#pragma unroll
        for (int ct = 0; ct < 4; ++ct) {
          int code = slab * 256 + wid * 64 + ct * 16 + l15;
          float t  = znr[rt][reg] + en_s[code];
          float dt = fmaf(-2.f, acc[rt][ct][reg], t);
          dm = fminf(dm, dt);
        }
#pragma unroll
        for (int m = 1; m < 16; m <<= 1) dm = fminf(dm, __shfl_xor(dm, m));
        if (l15 == 0) atomicMin(&rmin_s[row], __float_as_uint(dm));
      }
    __syncthreads();  // own+prior slab mins merged -> bounded thresholds

    // emission vs running min (monotone: races only ADD false positives)
#pragma unroll
    for (int rt = 0; rt < 2; ++rt)
#pragma unroll
      for (int reg = 0; reg < 4; ++reg) {
        int row = rt * 16 + l4 * 4 + reg;
        float thr = __uint_as_float(rmin_s[row]) + wr_s[row];
#pragma unroll
        for (int ct = 0; ct < 4; ++ct) {
          int code = slab * 256 + wid * 64 + ct * 16 + l15;
          float t  = znr[rt][reg] + en_s[code];
          float dt = fmaf(-2.f, acc[rt][ct][reg], t);
          if (dt <= thr) {
            int p = atomicAdd(&ccnt_s[row], 1);
            if (p < CAP) cand_s[row][p] = (unsigned short)code;
          }
        }
      }
    // no post-emission barrier (monotone-safe)
  }
  __syncthreads();  // all emissions done before refine

  // ---- exact refine: 8 threads per row (bitwise R3/R4/R5 chain) ----
  {
    const int sub  = tid >> 5;         // 0..7
    const int r    = tid & 31;
    const float* zp = z + (size_t)(rbase + r) * EDIM;
    float bd = 3.402823466e+38f;
    int   bi = 0x7FFFFFFF;
    int cnt = ccnt_s[r];
    if (cnt <= CAP) {
      for (int j = sub; j < cnt; j += 8) {
        int c = cand_s[r][j];
        const float* ep = emb + (size_t)c * EDIM;
        float p = 0.f;
#pragma unroll 8
        for (int k = 0; k < 256; ++k) p = fmaf(zp[k], ep[k], p);  // exact chain
        float t = zn_s[r] + en_s[c];
        float d = fmaf(-2.f, p, t);
        if (d < bd || (d == bd && c < bi)) { bd = d; bi = c; }
      }
    } else {  // overflow fallback: exact scan (correctness backstop)
      for (int c = sub; c < NE; c += 8) {
        const float* ep = emb + (size_t)c * EDIM;
        float p = 0.f;
#pragma unroll 8
        for (int k = 0; k < 256; ++k) p = fmaf(zp[k], ep[k], p);
        float t = zn_s[r] + en_s[c];
        float d = fmaf(-2.f, p, t);
        if (d < bd || (d == bd && c < bi)) { bd = d; bi = c; }
      }
    }
    bestd_s[r][sub] = bd;
    besti_s[r][sub] = bi;
  }
  __syncthreads();
  if (tid < 32) {
    float bd = bestd_s[tid][0];
    int   bi = besti_s[tid][0];
#pragma unroll
    for (int j = 1; j < 8; ++j) {
      float od = bestd_s[tid][j];
      int   oi = besti_s[tid][j];
      if (od < bd || (od == bd && oi < bi)) { bd = od; bi = oi; }
    }
    idx_s[tid] = bi;
    out[(size_t)OFF_IDX + rbase + tid] = (float)bi;
  }
  __syncthreads();  // idx_s ready; zero-fill long since drained by barriers

  // ---- fused scatter: STE + Spart (bitwise R4 tree) + hist + one-hot ----
#pragma unroll 1
  for (int rr = 0; rr < 8; ++rr) {
    int row_l = wid * 8 + rr;
    int row   = rbase + row_l;
    int idx   = idx_s[row_l];
    float4 zq = ((const float4*)(emb + (size_t)idx * EDIM))[lane];
    float4 zv = ((const float4*)(z + (size_t)row * EDIM))[lane];
    f32x4 st;
    st.x = zv.x + (zq.x - zv.x);
    st.y = zv.y + (zq.y - zv.y);
    st.z = zv.z + (zq.z - zv.z);
    st.w = zv.w + (zq.w - zv.w);
    __builtin_nontemporal_store(st, (f32x4*)(out + OFF_ZQ + (size_t)row * EDIM) + lane);
    float m  = (float)mask[row];
    float dx = __fmul_rn(__fsub_rn(zq.x, zv.x), m);
    float dy = __fmul_rn(__fsub_rn(zq.y, zv.y), m);
    float dz = __fmul_rn(__fsub_rn(zq.z, zv.z), m);
    float dw = __fmul_rn(__fsub_rn(zq.w, zv.w), m);
    float px = __fmul_rn(dx, dx);
    float py = __fmul_rn(dy, dy);
    float pz = __fmul_rn(dz, dz);
    float pw = __fmul_rn(dw, dw);
    float p  = __fadd_rn(__fadd_rn(px, py), __fadd_rn(pz, pw));
#pragma unroll
    for (int s = 1; s < 64; s <<= 1) p = __fadd_rn(p, __shfl_xor(p, s));
    if (lane == 0) {
      Spart[row] = p;
      atomicAdd(&hist[idx], 1u);
      out[(size_t)OFF_ENC + (size_t)row * NE + idx] = 1.0f;
    }
  }
}

// ---------------------------------------------------------------------------
// Kernel 2: finalize loss + perplexity (bitwise-unchanged from passing runs).
// ---------------------------------------------------------------------------
__global__ __launch_bounds__(1024) void k_final(const int* __restrict__ mask,
                                                const unsigned int* __restrict__ hist,
                                                const float* __restrict__ Spart,
                                                float* __restrict__ out) {
  int t = threadIdx.x;  // 1024
  int ms = 0;
  for (int i = t; i < NROWS; i += 1024) ms += mask[i];
  double sp = 0.0;
  for (int i = t; i < NROWS; i += 1024) sp += (double)Spart[i];
  double ent = 0.0;
  {
    int i = t;
    float em = (float)hist[i] * (1.0f / 65536.0f);   // exact
    float lg = logf(em + 1e-10f);
    ent = (double)(em * lg);
  }
#pragma unroll
  for (int m = 1; m < 64; m <<= 1) {
    ms  += __shfl_xor(ms, m);
    sp  += __shfl_xor(sp, m);
    ent += __shfl_xor(ent, m);
  }
  __shared__ double redS[16], redE[16];
  __shared__ int    redM[16];
  int w = t >> 6;
  if ((t & 63) == 0) { redS[w] = sp; redE[w] = ent; redM[w] = ms; }
  __syncthreads();
  if (t == 0) {
    double S = 0.0, E = 0.0; int M = 0;
    for (int i = 0; i < 16; ++i) { S += redS[i]; E += redE[i]; M += redM[i]; }
    float denom = (float)M + 1e-6f;
    float Sf    = (float)S;
    float cl    = Sf / denom;
    out[0] = cl + 0.25f * cl;
    out[(size_t)OFF_PERP] = expf((float)(-E));
  }
}

// ---------------------------------------------------------------------------
extern "C" void kernel_launch(void* const* d_in, const int* in_sizes, int n_in,
                              void* d_out, int out_size, void* d_ws, size_t ws_size,
                              hipStream_t stream) {
  const float* z    = (const float*)d_in[0];
  const int*   mask = (const int*)d_in[1];
  const float* emb  = (const float*)d_in[2];
  float*       out  = (float*)d_out;

  // ws (~795 KB): Spart | enorm | hist | emaxbits(+pad) | ebf16
  float*          Spart    = (float*)d_ws;                       // 65536 f32
  float*          enorm    = Spart + NROWS;                      // 1024 f32
  unsigned int*   hist     = (unsigned int*)(enorm + NE);        // 1024 u32
  int*            emaxbits = (int*)(hist + NE);                  // 1 i32 (+3 pad)
  unsigned short* ebf16    = (unsigned short*)(emaxbits + 4);    // 1024*256 bf16

  k_emb  <<<256,  256, 0, stream>>>(emb, enorm, ebf16, hist, emaxbits);
  k_main <<<2048, 256, 0, stream>>>(z, emb, ebf16, enorm, mask, emaxbits,
                                    out, hist, Spart);
  k_final<<<1,   1024, 0, stream>>>(mask, hist, Spart, out);
}